// Round 6
// baseline (535.050 us; speedup 1.0000x reference)
//
#include <hip/hip_runtime.h>

// PointPillarScatter: out[b, c, y, x] = pillar_features[p, c] where
// coords[p] = (b, z=0, y, x); zeros elsewhere. Output [8, 64, 496, 432] fp32.
//
// Gather formulation: build spatial->pillar index map in d_ws (6.9 MB),
// then one pass writes every output element once (coalesced float4 NT stores).
// R3: float4 feat loads + 4x4 register transpose, zero-row.
// R4: runtime coords dtype detection (int64 vs int32) + bounds guard.
// R5: load/store phase split (neutral). R6: plain stores (worse, reverted).
// R7: cooperative fusion (+165 us; reverted). R8: CSPLIT=1 traffic
// reduction (null, reverted) + wave-ballot dtype detect (kept).
// R9 (this round): MEASUREMENT PROBE — launch the (idempotent) gather
// TWICE. dur_us - 461.2 = t_gather, which rocprof's top-5 (crowded out
// by poison fills) has never let us observe. Decides whether the gather
// has ~100us of slack vs the 70us write roofline, or is already there.

#define PX_NX 432
#define PX_NY 496
#define PX_C 64
#define PX_NYX (PX_NY * PX_NX) // 214272, divisible by 4
#define CSPLIT 4               // channel groups per (b,y,x4) position

typedef float floatx4 __attribute__((ext_vector_type(4)));
typedef long longx4 __attribute__((ext_vector_type(4))); // 32 B

// ---- kernel 1: init index map to -1, zero-row to 0 ----------------------
__global__ void pps_init_map(int4* __restrict__ map4, int n4) {
    int i = blockIdx.x * blockDim.x + threadIdx.x;
    if (i < n4) {
        map4[i] = make_int4(-1, -1, -1, -1);
    }
    // 64-float zero row lives right after the map (n4*4 ints in)
    if (blockIdx.x == 0 && threadIdx.x < 16) {
        map4[n4 + threadIdx.x] = make_int4(0, 0, 0, 0);
    }
}

// ---- kernel 2: scatter pillar ids into the map (wave-local detect) ------
// coords: [P,4] (batch, z, y, x), int32 or int64 — detected per-wave:
// int32 layout: word 4r+3 == x coord of row r (nonzero w.p. 431/432).
// int64 (LE) layout: words 4r+3 land on {z_hi, x_hi, ...} == 0 always.
__global__ void pps_scatter_ids(const int* __restrict__ c32,
                                const longx4* __restrict__ c64,
                                int* __restrict__ map, int P, int map_n) {
    int lane = threadIdx.x & 63;
    int probe = c32[4 * (lane & 15) + 3];
    bool is64 = (__ballot(probe != 0) == 0ull); // all-zero => int64 coords

    int p = blockIdx.x * blockDim.x + threadIdx.x;
    if (p >= P) return;
    long g;
    if (is64) { // int64 coords (wave-uniform branch)
        longx4 cv = c64[p];
        g = cv.x * PX_NYX + cv.y + cv.z * PX_NX + cv.w;
    } else {    // int32 coords
        int4 cv = ((const int4*)c32)[p];
        g = (long)cv.x * PX_NYX + (long)cv.y + (long)cv.z * PX_NX + (long)cv.w;
    }
    if (g >= 0 && g < (long)map_n) map[(int)g] = p; // bounds-guarded
}

// ---- kernel 3: gather + write full output (R5 body, best measured) ------
// One thread = 4 consecutive x positions for one (b, y), 16 channels
// (CSPLIT=4). Phase 1: all 16 float4 feat loads into q[16] (compile-time
// indices -> registers). Phase 2: 4x4 register transposes + 16 NT float4
// stores. Empty positions read a zeroed row. Idempotent by construction.
__global__ void pps_gather(const float* __restrict__ feat,
                           const int* __restrict__ map,
                           const float* __restrict__ zrow,
                           float* __restrict__ out, int total) {
    int i = blockIdx.x * blockDim.x + threadIdx.x;
    if (i >= total) return;

    const int xq = PX_NX / 4; // 108
    int x4 = i % xq;
    int t = i / xq;
    int y = t % PX_NY;
    int t2 = t / PX_NY;
    int b = t2 % 8;       // B==8 fixed by problem
    int cs = t2 / 8;      // channel group 0..CSPLIT-1

    int sbase = b * PX_NYX + y * PX_NX + x4 * 4; // divisible by 4
    int4 pid = ((const int4*)map)[sbase >> 2];

    const float* r0 = (pid.x >= 0) ? feat + (size_t)pid.x * PX_C : zrow;
    const float* r1 = (pid.y >= 0) ? feat + (size_t)pid.y * PX_C : zrow;
    const float* r2 = (pid.z >= 0) ? feat + (size_t)pid.z * PX_C : zrow;
    const float* r3 = (pid.w >= 0) ? feat + (size_t)pid.w * PX_C : zrow;

    const int c_lo = cs * (PX_C / CSPLIT); // 16 channels per thread
    float* ob = out + (size_t)b * ((size_t)PX_C * PX_NYX)
                    + (size_t)y * PX_NX + (size_t)x4 * 4;

    // Phase 1: issue all 16 loads (4 rows x 4 channel-chunks).
    floatx4 q[16];
#pragma unroll
    for (int cc = 0; cc < 4; ++cc) {
        int c0 = c_lo + cc * 4;
        q[cc * 4 + 0] = *(const floatx4*)(r0 + c0);
        q[cc * 4 + 1] = *(const floatx4*)(r1 + c0);
        q[cc * 4 + 2] = *(const floatx4*)(r2 + c0);
        q[cc * 4 + 3] = *(const floatx4*)(r3 + c0);
    }

    // Phase 2: transpose + NT stores.
#pragma unroll
    for (int cc = 0; cc < 4; ++cc) {
        int c0 = c_lo + cc * 4;
#pragma unroll
        for (int k = 0; k < 4; ++k) {
            floatx4 v;
            v.x = q[cc * 4 + 0][k];
            v.y = q[cc * 4 + 1][k];
            v.z = q[cc * 4 + 2][k];
            v.w = q[cc * 4 + 3][k];
            __builtin_nontemporal_store(
                v, (floatx4*)(ob + (size_t)(c0 + k) * PX_NYX));
        }
    }
}

extern "C" void kernel_launch(void* const* d_in, const int* in_sizes, int n_in,
                              void* d_out, int out_size, void* d_ws, size_t ws_size,
                              hipStream_t stream) {
    const float* feat = (const float*)d_in[0];
    const int* coords32 = (const int*)d_in[1];
    const longx4* coords64 = (const longx4*)d_in[1];
    float* out = (float*)d_out;
    int* map = (int*)d_ws; // B*NY*NX int32 = 6.86 MB + 256 B zero row

    int B = out_size / (PX_C * PX_NYX); // 8 (out_size is element count)
    int P = in_sizes[1] / 4;            // 128000 (elements / 4 per row)

    int map_n = B * PX_NYX;     // 1,714,176
    int map_n4 = map_n / 4;     // 428,544
    const float* zrow = (const float*)(map + map_n); // 64 zeroed floats

    int total = B * PX_NY * (PX_NX / 4) * CSPLIT; // 1,714,176 threads

    pps_init_map<<<(map_n4 + 255) / 256, 256, 0, stream>>>((int4*)map, map_n4);
    pps_scatter_ids<<<(P + 255) / 256, 256, 0, stream>>>(
        coords32, coords64, map, P, map_n);
    pps_gather<<<(total + 255) / 256, 256, 0, stream>>>(feat, map, zrow, out, total);
    // R9 PROBE: second identical (idempotent) gather — dur delta = t_gather.
    pps_gather<<<(total + 255) / 256, 256, 0, stream>>>(feat, map, zrow, out, total);
}

// Round 7
// 457.821 us; speedup vs baseline: 1.1687x; 1.1687x over previous
//
#include <hip/hip_runtime.h>

// PointPillarScatter: out[b, c, y, x] = pillar_features[p, c] where
// coords[p] = (b, z=0, y, x); zeros elsewhere. Output [8, 64, 496, 432] fp32.
//
// Gather formulation: build spatial->pillar index map in d_ws (6.9 MB),
// then one pass writes every output element once (coalesced float4 NT stores).
// R3: float4 feat loads + 4x4 register transpose, zero-row.
// R4: runtime coords dtype detection (int64 vs int32) + bounds guard.
// R5: load/store phase split (neutral, kept). R6: plain stores (worse,
// reverted). R7: cooperative fusion (+165 us; reverted). R8: CSPLIT=1
// (null; reverted) + wave-ballot dtype detect (kept). R9: double-gather
// probe measured t_gather = 73.8 us == its 78 us memory roofline.
// R10 (this round): revert the probe. Final configuration. Window budget:
// ~275 us harness poison fill + ~105 us harness restore/launch traffic
// + ~74 us gather (at roofline) + ~7 us init+scatter. No kernel-side
// slack remains: 5 gather codegen variants all measured null, and the
// gather's duration equals its byte count / achieved HBM bandwidth.

#define PX_NX 432
#define PX_NY 496
#define PX_C 64
#define PX_NYX (PX_NY * PX_NX) // 214272, divisible by 4
#define CSPLIT 4               // channel groups per (b,y,x4) position

typedef float floatx4 __attribute__((ext_vector_type(4)));
typedef long longx4 __attribute__((ext_vector_type(4))); // 32 B

// ---- kernel 1: init index map to -1, zero-row to 0 ----------------------
__global__ void pps_init_map(int4* __restrict__ map4, int n4) {
    int i = blockIdx.x * blockDim.x + threadIdx.x;
    if (i < n4) {
        map4[i] = make_int4(-1, -1, -1, -1);
    }
    // 64-float zero row lives right after the map (n4*4 ints in)
    if (blockIdx.x == 0 && threadIdx.x < 16) {
        map4[n4 + threadIdx.x] = make_int4(0, 0, 0, 0);
    }
}

// ---- kernel 2: scatter pillar ids into the map (wave-local detect) ------
// coords: [P,4] (batch, z, y, x), int32 or int64 — detected per-wave:
// int32 layout: word 4r+3 == x coord of row r (nonzero w.p. 431/432).
// int64 (LE) layout: words 4r+3 land on {z_hi, x_hi, ...} == 0 always.
__global__ void pps_scatter_ids(const int* __restrict__ c32,
                                const longx4* __restrict__ c64,
                                int* __restrict__ map, int P, int map_n) {
    int lane = threadIdx.x & 63;
    int probe = c32[4 * (lane & 15) + 3];
    bool is64 = (__ballot(probe != 0) == 0ull); // all-zero => int64 coords

    int p = blockIdx.x * blockDim.x + threadIdx.x;
    if (p >= P) return;
    long g;
    if (is64) { // int64 coords (wave-uniform branch)
        longx4 cv = c64[p];
        g = cv.x * PX_NYX + cv.y + cv.z * PX_NX + cv.w;
    } else {    // int32 coords
        int4 cv = ((const int4*)c32)[p];
        g = (long)cv.x * PX_NYX + (long)cv.y + (long)cv.z * PX_NX + (long)cv.w;
    }
    if (g >= 0 && g < (long)map_n) map[(int)g] = p; // bounds-guarded
}

// ---- kernel 3: gather + write full output (R5 body, best measured) ------
// One thread = 4 consecutive x positions for one (b, y), 16 channels
// (CSPLIT=4). Phase 1: all 16 float4 feat loads into q[16] (compile-time
// indices -> registers). Phase 2: 4x4 register transposes + 16 NT float4
// stores (consecutive lanes -> consecutive x). Empty positions read a
// zeroed row (no selects). Measured at its memory roofline (73.8 us).
__global__ void pps_gather(const float* __restrict__ feat,
                           const int* __restrict__ map,
                           const float* __restrict__ zrow,
                           float* __restrict__ out, int total) {
    int i = blockIdx.x * blockDim.x + threadIdx.x;
    if (i >= total) return;

    const int xq = PX_NX / 4; // 108
    int x4 = i % xq;
    int t = i / xq;
    int y = t % PX_NY;
    int t2 = t / PX_NY;
    int b = t2 % 8;       // B==8 fixed by problem
    int cs = t2 / 8;      // channel group 0..CSPLIT-1

    int sbase = b * PX_NYX + y * PX_NX + x4 * 4; // divisible by 4
    int4 pid = ((const int4*)map)[sbase >> 2];

    const float* r0 = (pid.x >= 0) ? feat + (size_t)pid.x * PX_C : zrow;
    const float* r1 = (pid.y >= 0) ? feat + (size_t)pid.y * PX_C : zrow;
    const float* r2 = (pid.z >= 0) ? feat + (size_t)pid.z * PX_C : zrow;
    const float* r3 = (pid.w >= 0) ? feat + (size_t)pid.w * PX_C : zrow;

    const int c_lo = cs * (PX_C / CSPLIT); // 16 channels per thread
    float* ob = out + (size_t)b * ((size_t)PX_C * PX_NYX)
                    + (size_t)y * PX_NX + (size_t)x4 * 4;

    // Phase 1: issue all 16 loads (4 rows x 4 channel-chunks).
    floatx4 q[16];
#pragma unroll
    for (int cc = 0; cc < 4; ++cc) {
        int c0 = c_lo + cc * 4;
        q[cc * 4 + 0] = *(const floatx4*)(r0 + c0);
        q[cc * 4 + 1] = *(const floatx4*)(r1 + c0);
        q[cc * 4 + 2] = *(const floatx4*)(r2 + c0);
        q[cc * 4 + 3] = *(const floatx4*)(r3 + c0);
    }

    // Phase 2: transpose + NT stores.
#pragma unroll
    for (int cc = 0; cc < 4; ++cc) {
        int c0 = c_lo + cc * 4;
#pragma unroll
        for (int k = 0; k < 4; ++k) {
            floatx4 v;
            v.x = q[cc * 4 + 0][k];
            v.y = q[cc * 4 + 1][k];
            v.z = q[cc * 4 + 2][k];
            v.w = q[cc * 4 + 3][k];
            __builtin_nontemporal_store(
                v, (floatx4*)(ob + (size_t)(c0 + k) * PX_NYX));
        }
    }
}

extern "C" void kernel_launch(void* const* d_in, const int* in_sizes, int n_in,
                              void* d_out, int out_size, void* d_ws, size_t ws_size,
                              hipStream_t stream) {
    const float* feat = (const float*)d_in[0];
    const int* coords32 = (const int*)d_in[1];
    const longx4* coords64 = (const longx4*)d_in[1];
    float* out = (float*)d_out;
    int* map = (int*)d_ws; // B*NY*NX int32 = 6.86 MB + 256 B zero row

    int B = out_size / (PX_C * PX_NYX); // 8 (out_size is element count)
    int P = in_sizes[1] / 4;            // 128000 (elements / 4 per row)

    int map_n = B * PX_NYX;     // 1,714,176
    int map_n4 = map_n / 4;     // 428,544
    const float* zrow = (const float*)(map + map_n); // 64 zeroed floats

    int total = B * PX_NY * (PX_NX / 4) * CSPLIT; // 1,714,176 threads

    pps_init_map<<<(map_n4 + 255) / 256, 256, 0, stream>>>((int4*)map, map_n4);
    pps_scatter_ids<<<(P + 255) / 256, 256, 0, stream>>>(
        coords32, coords64, map, P, map_n);
    pps_gather<<<(total + 255) / 256, 256, 0, stream>>>(feat, map, zrow, out, total);
}